// Round 6
// baseline (1151.458 us; speedup 1.0000x reference)
//
#include <hip/hip_runtime.h>
#include <hip/hip_bf16.h>
#include <math.h>

typedef __attribute__((ext_vector_type(8))) short bf8_t;   // 8 x bf16 (4 VGPRs)
typedef __attribute__((ext_vector_type(4))) float f4_t;    // MFMA accumulator
typedef __attribute__((ext_vector_type(8))) unsigned short us8_t;

__device__ inline unsigned short f2bf(float f) {
  union { float f; unsigned u; } x; x.f = f;
  unsigned r = x.u + 0x7FFF + ((x.u >> 16) & 1);   // RNE
  return (unsigned short)(r >> 16);
}
__device__ inline float bf2f(unsigned short b) {
  union { unsigned u; float f; } x; x.u = ((unsigned)b) << 16;
  return x.f;
}
// packed-pair helpers: lo/hi bf16 of a uint -> float
__device__ inline float bflo(unsigned v) {
  union { unsigned u; float f; } x; x.u = v << 16; return x.f;
}
__device__ inline float bfhi(unsigned v) {
  union { unsigned u; float f; } x; x.u = v & 0xFFFF0000u; return x.f;
}

// ---------------------------------------------------------------------------
// small utility kernels
// ---------------------------------------------------------------------------

__global__ void k_fill1(float* __restrict__ p, int n) {
  int i = blockIdx.x * blockDim.x + threadIdx.x;
  if (i < n) p[i] = 1.0f;
}

__global__ void k_zero_i(int* __restrict__ p, int n) {
  int i = blockIdx.x * blockDim.x + threadIdx.x;
  if (i < n) p[i] = 0;
}

__global__ void k_scatter_deg(const int* __restrict__ dst, const float* __restrict__ ew,
                              float* __restrict__ deg, int E) {
  int e = blockIdx.x * blockDim.x + threadIdx.x;
  if (e < E) atomicAdd(&deg[dst[e]], ew[e]);
}

__global__ void k_count(const int* __restrict__ dst, int* __restrict__ cnt, int E) {
  int e = blockIdx.x * blockDim.x + threadIdx.x;
  if (e < E) atomicAdd(&cnt[dst[e]], 1);
}

__global__ void k_rsqrt(float* __restrict__ p, int n) {
  int i = blockIdx.x * blockDim.x + threadIdx.x;
  if (i < n) p[i] = rsqrtf(p[i]);
}

// fp32 -> bf16 bulk convert (n multiple of 8)
__global__ void k_f2bf(const float* __restrict__ in, unsigned short* __restrict__ out,
                       size_t n8) {
  size_t i = (size_t)blockIdx.x * blockDim.x + threadIdx.x;
  if (i >= n8) return;
  const float4* p = (const float4*)(in + i * 8);
  float4 a = p[0], b = p[1];
  us8_t v;
  v[0] = f2bf(a.x); v[1] = f2bf(a.y); v[2] = f2bf(a.z); v[3] = f2bf(a.w);
  v[4] = f2bf(b.x); v[5] = f2bf(b.y); v[6] = f2bf(b.z); v[7] = f2bf(b.w);
  *(us8_t*)(out + i * 8) = v;
}

// pack weight matrix into MFMA B-fragment order (16x16x32 bf16).
// B[k][n] = trans ? W[n*ldw+k] : W[k*ldw+n]
// fragment (n0,k0): lane holds B[k0*32+(lane>>4)*8+j][n0*16+(lane&15)], j=0..7
__global__ void k_packB(const float* __restrict__ W, unsigned short* __restrict__ out,
                        int K, int Ncols, int ldw, int trans) {
  int idx = blockIdx.x * 256 + threadIdx.x;
  int total = (Ncols / 16) * (K / 32) * 64;
  if (idx >= total) return;
  int lane = idx & 63;
  int frag = idx >> 6;
  int kt = K / 32;
  int k0 = frag % kt;
  int n0 = frag / kt;
  int n = n0 * 16 + (lane & 15);
  int kbase = k0 * 32 + (lane >> 4) * 8;
  us8_t v;
#pragma unroll
  for (int j = 0; j < 8; ++j) {
    int k = kbase + j;
    float f = trans ? W[(size_t)n * ldw + k] : W[(size_t)k * ldw + n];
    v[j] = f2bf(f);
  }
  *(us8_t*)(out + (size_t)idx * 8) = v;
}

// ---------------------------------------------------------------------------
// hierarchical scan for rowptr (N up to 512*256 = 131072)
// ---------------------------------------------------------------------------

__global__ __launch_bounds__(256) void k_scan_block(
    const int* __restrict__ cnt, int* __restrict__ partial,
    int* __restrict__ bsum, int n) {
  __shared__ int s[256];
  int tid = threadIdx.x;
  int i = blockIdx.x * 256 + tid;
  s[tid] = (i < n) ? cnt[i] : 0;
  __syncthreads();
#pragma unroll
  for (int d = 1; d < 256; d <<= 1) {
    int t = (tid >= d) ? s[tid - d] : 0;
    __syncthreads();
    s[tid] += t;
    __syncthreads();
  }
  if (i < n) partial[i] = s[tid];
  if (tid == 255) bsum[blockIdx.x] = s[255];
}

__global__ __launch_bounds__(512) void k_scan_sums(int* __restrict__ bsum, int nb) {
  __shared__ int s[512];
  int tid = threadIdx.x;
  s[tid] = (tid < nb) ? bsum[tid] : 0;
  __syncthreads();
#pragma unroll
  for (int d = 1; d < 512; d <<= 1) {
    int t = (tid >= d) ? s[tid - d] : 0;
    __syncthreads();
    s[tid] += t;
    __syncthreads();
  }
  if (tid < nb) bsum[tid] = s[tid];
}

__global__ __launch_bounds__(256) void k_scan_add(
    const int* __restrict__ partial, const int* __restrict__ bsum,
    int* __restrict__ rowptr, int* __restrict__ cursor, int n) {
  int i = blockIdx.x * 256 + threadIdx.x;
  if (i == 0) { rowptr[0] = 0; cursor[0] = 0; }
  if (i < n) {
    int v = partial[i] + (blockIdx.x > 0 ? bsum[blockIdx.x - 1] : 0);
    rowptr[i + 1] = v;
    if (i + 1 < n) cursor[i + 1] = v;
  }
}

// scatter edges into CSR slots; record = (src, weight-bits) packed int2
__global__ __launch_bounds__(256) void k_csr_fill(
    const int* __restrict__ src, const int* __restrict__ dst,
    const float* __restrict__ ew, const float* __restrict__ dinv,
    int* __restrict__ cursor, int2* __restrict__ csr, int E) {
  int e = blockIdx.x * 256 + threadIdx.x;
  if (e >= E) return;
  int s = src[e], d = dst[e];
  float w = dinv[s] * ew[e] * dinv[d];
  int pos = atomicAdd(&cursor[d], 1);
  csr[pos] = make_int2(s, __float_as_int(w));
}

// ---------------------------------------------------------------------------
// MFMA GEMM: C[M,128] = A[M,128] @ B[128,128] (+bias)(+relu), bf16 in/out.
// 32 rows per wave (2 row-tiles): each B-fragment load feeds 2 MFMAs.
// ---------------------------------------------------------------------------

template<bool RELU, bool BIAS>
__global__ __launch_bounds__(256) void k_mfma_gemm(
    const unsigned short* __restrict__ A, const unsigned short* __restrict__ Bp,
    const float* __restrict__ bias, unsigned short* __restrict__ C, int M) {
  int wave = threadIdx.x >> 6, lane = threadIdx.x & 63;
  int row0 = (blockIdx.x * 4 + wave) * 32;
  if (row0 >= M) return;
  int m = lane & 15, q = lane >> 4;
  bf8_t a[2][4];
#pragma unroll
  for (int t = 0; t < 2; ++t) {
    int arow = row0 + t * 16 + m; if (arow >= M) arow = M - 1;
#pragma unroll
    for (int k0 = 0; k0 < 4; ++k0)
      a[t][k0] = *(const bf8_t*)(A + (size_t)arow * 128 + k0 * 32 + q * 8);
  }
#pragma unroll
  for (int n0 = 0; n0 < 8; ++n0) {
    f4_t acc0 = {}, acc1 = {};
#pragma unroll
    for (int k0 = 0; k0 < 4; ++k0) {
      bf8_t b = *(const bf8_t*)(Bp + ((size_t)(n0 * 4 + k0) * 64 + lane) * 8);
      acc0 = __builtin_amdgcn_mfma_f32_16x16x32_bf16(a[0][k0], b, acc0, 0, 0, 0);
      acc1 = __builtin_amdgcn_mfma_f32_16x16x32_bf16(a[1][k0], b, acc1, 0, 0, 0);
    }
    int col = n0 * 16 + m;
    float bs = BIAS ? bias[col] : 0.f;
#pragma unroll
    for (int r = 0; r < 4; ++r) {
      int g0 = row0 + q * 4 + r;
      if (g0 < M) {
        float v = acc0[r] + bs;
        if (RELU) v = fmaxf(v, 0.f);
        C[(size_t)g0 * 128 + col] = f2bf(v);
      }
      int g1 = row0 + 16 + q * 4 + r;
      if (g1 < M) {
        float v = acc1[r] + bs;
        if (RELU) v = fmaxf(v, 0.f);
        C[(size_t)g1 * 128 + col] = f2bf(v);
      }
    }
  }
}

// ---------------------------------------------------------------------------
// Fused MFMA GRU. Wave owns 32 rows (2 row-tiles); B loads amortized 2x.
// In-place h safe: wave reads/writes only its own rows.
// ---------------------------------------------------------------------------

__global__ __launch_bounds__(256) void k_gru_mfma(
    const unsigned short* __restrict__ xh,  // [M,128] bf16
    const float* h_in,                      // [M,128] fp32
    float* h_out,                           // [M,128] fp32 (may alias h_in)
    const unsigned short* __restrict__ Bi,  // packed WihT (K=128, Ncols=384)
    const unsigned short* __restrict__ Bh,  // packed WhhT
    const float* __restrict__ bih, const float* __restrict__ bhh, int M) {
  int wave = threadIdx.x >> 6, lane = threadIdx.x & 63;
  int row0 = (blockIdx.x * 4 + wave) * 32;
  if (row0 >= M) return;
  int m = lane & 15, q = lane >> 4;

  bf8_t ax[2][4], ah[2][4];
#pragma unroll
  for (int t = 0; t < 2; ++t) {
    int arow = row0 + t * 16 + m; if (arow >= M) arow = M - 1;
#pragma unroll
    for (int k0 = 0; k0 < 4; ++k0) {
      ax[t][k0] = *(const bf8_t*)(xh + (size_t)arow * 128 + k0 * 32 + q * 8);
      const float* hp = h_in + (size_t)arow * 128 + k0 * 32 + q * 8;
      float4 h0 = *(const float4*)hp;
      float4 h1 = *(const float4*)(hp + 4);
      bf8_t tt;
      tt[0] = (short)f2bf(h0.x); tt[1] = (short)f2bf(h0.y);
      tt[2] = (short)f2bf(h0.z); tt[3] = (short)f2bf(h0.w);
      tt[4] = (short)f2bf(h1.x); tt[5] = (short)f2bf(h1.y);
      tt[6] = (short)f2bf(h1.z); tt[7] = (short)f2bf(h1.w);
      ah[t][k0] = tt;
    }
  }

  for (int g = 0; g < 8; ++g) {
    f4_t air[2] = {}, aiz[2] = {}, ain[2] = {};
    f4_t ahr[2] = {}, ahz[2] = {}, ahn[2] = {};
#pragma unroll
    for (int k0 = 0; k0 < 4; ++k0) {
      bf8_t br = *(const bf8_t*)(Bi + ((size_t)((g     ) * 4 + k0) * 64 + lane) * 8);
      bf8_t bz = *(const bf8_t*)(Bi + ((size_t)((g +  8) * 4 + k0) * 64 + lane) * 8);
      bf8_t bn = *(const bf8_t*)(Bi + ((size_t)((g + 16) * 4 + k0) * 64 + lane) * 8);
      bf8_t cr = *(const bf8_t*)(Bh + ((size_t)((g     ) * 4 + k0) * 64 + lane) * 8);
      bf8_t cz = *(const bf8_t*)(Bh + ((size_t)((g +  8) * 4 + k0) * 64 + lane) * 8);
      bf8_t cn = *(const bf8_t*)(Bh + ((size_t)((g + 16) * 4 + k0) * 64 + lane) * 8);
#pragma unroll
      for (int t = 0; t < 2; ++t) {
        air[t] = __builtin_amdgcn_mfma_f32_16x16x32_bf16(ax[t][k0], br, air[t], 0, 0, 0);
        aiz[t] = __builtin_amdgcn_mfma_f32_16x16x32_bf16(ax[t][k0], bz, aiz[t], 0, 0, 0);
        ain[t] = __builtin_amdgcn_mfma_f32_16x16x32_bf16(ax[t][k0], bn, ain[t], 0, 0, 0);
        ahr[t] = __builtin_amdgcn_mfma_f32_16x16x32_bf16(ah[t][k0], cr, ahr[t], 0, 0, 0);
        ahz[t] = __builtin_amdgcn_mfma_f32_16x16x32_bf16(ah[t][k0], cz, ahz[t], 0, 0, 0);
        ahn[t] = __builtin_amdgcn_mfma_f32_16x16x32_bf16(ah[t][k0], cn, ahn[t], 0, 0, 0);
      }
    }
    int col = g * 16 + m;
    float bir_ = bih[col], biz_ = bih[col + 128], bin_ = bih[col + 256];
    float bhr_ = bhh[col], bhz_ = bhh[col + 128], bhn_ = bhh[col + 256];
#pragma unroll
    for (int t = 0; t < 2; ++t) {
#pragma unroll
      for (int r = 0; r < 4; ++r) {
        int grow = row0 + t * 16 + q * 4 + r;
        if (grow < M) {
          float hprev = h_in[(size_t)grow * 128 + col];
          float rr = 1.f / (1.f + expf(-(air[t][r] + bir_ + ahr[t][r] + bhr_)));
          float zz = 1.f / (1.f + expf(-(aiz[t][r] + biz_ + ahz[t][r] + bhz_)));
          float nn = tanhf(ain[t][r] + bin_ + rr * (ahn[t][r] + bhn_));
          h_out[(size_t)grow * 128 + col] = (1.f - zz) * nn + zz * hprev;
        }
      }
    }
  }
}

// ---------------------------------------------------------------------------
// fp32 GEMM (final fc layer)
// ---------------------------------------------------------------------------

template<bool RELU, bool BIAS>
__global__ __launch_bounds__(256) void k_gemm128(
    const float* __restrict__ A, const float* __restrict__ B,
    const float* __restrict__ bias, float* __restrict__ C, int M, int Nc) {
  __shared__ float As[64][36];
  __shared__ float Bs[32][64];
  int tid = threadIdx.x;
  int tx = tid & 15, ty = tid >> 4;
  int row0 = blockIdx.y * 64, col0 = blockIdx.x * 64;
  float acc[4][4] = {};

  for (int k0 = 0; k0 < 128; k0 += 32) {
#pragma unroll
    for (int i = 0; i < 2; ++i) {
      int f = tid + i * 256;
      int r = f >> 3, c4 = f & 7;
      int gr = row0 + r;
      float4 v = make_float4(0.f, 0.f, 0.f, 0.f);
      if (gr < M) v = *(const float4*)(A + (size_t)gr * 128 + k0 + c4 * 4);
      *(float4*)(&As[r][c4 * 4]) = v;
    }
#pragma unroll
    for (int i = 0; i < 2; ++i) {
      int f = tid + i * 256;
      int r = f >> 4, c4 = f & 15;
      int gc = col0 + c4 * 4;
      float4 v = make_float4(0.f, 0.f, 0.f, 0.f);
      if (gc + 3 < Nc) v = *(const float4*)(B + (size_t)(k0 + r) * Nc + gc);
      *(float4*)(&Bs[r][c4 * 4]) = v;
    }
    __syncthreads();
#pragma unroll
    for (int kk = 0; kk < 32; ++kk) {
      float4 b = *(float4*)(&Bs[kk][tx * 4]);
      float a0 = As[ty * 4 + 0][kk];
      float a1 = As[ty * 4 + 1][kk];
      float a2 = As[ty * 4 + 2][kk];
      float a3 = As[ty * 4 + 3][kk];
      acc[0][0] += a0 * b.x; acc[0][1] += a0 * b.y; acc[0][2] += a0 * b.z; acc[0][3] += a0 * b.w;
      acc[1][0] += a1 * b.x; acc[1][1] += a1 * b.y; acc[1][2] += a1 * b.z; acc[1][3] += a1 * b.w;
      acc[2][0] += a2 * b.x; acc[2][1] += a2 * b.y; acc[2][2] += a2 * b.z; acc[2][3] += a2 * b.w;
      acc[3][0] += a3 * b.x; acc[3][1] += a3 * b.y; acc[3][2] += a3 * b.z; acc[3][3] += a3 * b.w;
    }
    __syncthreads();
  }

#pragma unroll
  for (int i = 0; i < 4; ++i) {
    int gr = row0 + ty * 4 + i;
    if (gr >= M) continue;
#pragma unroll
    for (int j = 0; j < 4; ++j) {
      int gc = col0 + tx * 4 + j;
      if (gc >= Nc) continue;
      float v = acc[i][j];
      if (BIAS) v += bias[gc];
      if (RELU) v = fmaxf(v, 0.f);
      C[(size_t)gr * Nc + gc] = v;
    }
  }
}

// ---------------------------------------------------------------------------
// CSR gather aggregation: 1 node per wave, lane owns 2 channels (packed uint).
// ---------------------------------------------------------------------------

__global__ __launch_bounds__(256) void k_gather(
    const int* __restrict__ rowptr, const int2* __restrict__ csr,
    const unsigned* __restrict__ xw,   // [N,64] packed bf16x2
    const float* __restrict__ dinv, const float* __restrict__ bias,
    unsigned* __restrict__ out, int N) {
  int wave = threadIdx.x >> 6;
  int lane = threadIdx.x & 63;
  int node = __builtin_amdgcn_readfirstlane(blockIdx.x * 4 + wave);
  if (node >= N) return;
  int beg = __builtin_amdgcn_readfirstlane(rowptr[node]);
  int end = __builtin_amdgcn_readfirstlane(rowptr[node + 1]);

  float accl = 0.f, acch = 0.f;
  int k = beg;
  for (; k + 4 <= end; k += 4) {
    int2 e0 = csr[k], e1 = csr[k + 1], e2 = csr[k + 2], e3 = csr[k + 3];
    unsigned v0 = xw[((size_t)e0.x << 6) + lane];
    unsigned v1 = xw[((size_t)e1.x << 6) + lane];
    unsigned v2 = xw[((size_t)e2.x << 6) + lane];
    unsigned v3 = xw[((size_t)e3.x << 6) + lane];
    float w0 = __int_as_float(e0.y), w1 = __int_as_float(e1.y);
    float w2 = __int_as_float(e2.y), w3 = __int_as_float(e3.y);
    accl += bflo(v0) * w0; acch += bfhi(v0) * w0;
    accl += bflo(v1) * w1; acch += bfhi(v1) * w1;
    accl += bflo(v2) * w2; acch += bfhi(v2) * w2;
    accl += bflo(v3) * w3; acch += bfhi(v3) * w3;
  }
  for (; k < end; ++k) {
    int2 e = csr[k];
    unsigned v = xw[((size_t)e.x << 6) + lane];
    float w = __int_as_float(e.y);
    accl += bflo(v) * w; acch += bfhi(v) * w;
  }

  float di = dinv[node];
  float sn = di * di;
  unsigned vs = xw[((size_t)node << 6) + lane];
  float2 b = *(const float2*)(bias + lane * 2);
  float rl = fmaxf(accl + bflo(vs) * sn + b.x, 0.f);
  float rh = fmaxf(acch + bfhi(vs) * sn + b.y, 0.f);
  unsigned o = (unsigned)f2bf(rl) | ((unsigned)f2bf(rh) << 16);
  out[((size_t)node << 6) + lane] = o;
}

// ---------------------------------------------------------------------------

extern "C" void kernel_launch(void* const* d_in, const int* in_sizes, int n_in,
                              void* d_out, int out_size, void* d_ws, size_t ws_size,
                              hipStream_t stream) {
  const float* x    = (const float*)d_in[0];
  const int*   ei   = (const int*)d_in[1];
  const float* ew   = (const float*)d_in[2];
  const float* h0   = (const float*)d_in[3];
  const float* linW = (const float*)d_in[4];
  const float* linB = (const float*)d_in[5];
  const float* convW= (const float*)d_in[6];
  const float* convB= (const float*)d_in[7];
  const float* Wih  = (const float*)d_in[8];
  const float* Whh  = (const float*)d_in[9];
  const float* bih  = (const float*)d_in[10];
  const float* bhh  = (const float*)d_in[11];
  const float* fcW  = (const float*)d_in[12];
  const float* fcB  = (const float*)d_in[13];

  int N = in_sizes[0] / 128;
  int E = in_sizes[1] / 2;
  const int* srcI = ei;
  const int* dstI = ei + E;
  int nb = (N + 255) / 256;

  // ---- workspace layout ----
  float* ws = (float*)d_ws;
  size_t off = 0;
  float* dinv = ws + off; off += (size_t)N;
  if (off & 1) off++;                       // 8B-align what follows
  float* h    = ws + off; off += (size_t)N * 128;
  int* iws = (int*)(ws + off);              // 8B-aligned
  size_t ioff = 0;
  int2* csr    = (int2*)iws; ioff += (size_t)2 * E;
  int* cnt     = iws + ioff; ioff += (size_t)N;
  int* partial = iws + ioff; ioff += (size_t)N;
  int* bsum    = iws + ioff; ioff += 512;
  int* rowptr  = iws + ioff; ioff += (size_t)N + 1;
  int* cursor  = iws + ioff; ioff += (size_t)N;
  ioff = (ioff + 3) & ~(size_t)3;           // 16B-align ushort area
  unsigned short* usws = (unsigned short*)(iws + ioff);
  size_t uoff = 0;
  unsigned short* x_bf   = usws + uoff; uoff += (size_t)N * 128;
  unsigned short* xh_bf  = usws + uoff; uoff += (size_t)N * 128;
  unsigned short* xw_bf  = usws + uoff; uoff += (size_t)N * 128;
  unsigned short* linWp  = usws + uoff; uoff += 128 * 128;
  unsigned short* convWp = usws + uoff; uoff += 3 * 128 * 128;
  unsigned short* Bi     = usws + uoff; uoff += 384 * 128;
  unsigned short* Bh     = usws + uoff; uoff += 384 * 128;

  // ---- weight packing ----
  k_packB<<<(8 * 4 * 64 + 255) / 256, 256, 0, stream>>>(linW, linWp, 128, 128, 128, 0);
  for (int l = 0; l < 3; ++l)
    k_packB<<<(8 * 4 * 64 + 255) / 256, 256, 0, stream>>>(
        convW + (size_t)l * 128 * 128, convWp + (size_t)l * 128 * 128, 128, 128, 128, 0);
  k_packB<<<(24 * 4 * 64 + 255) / 256, 256, 0, stream>>>(Wih, Bi, 128, 384, 128, 1);
  k_packB<<<(24 * 4 * 64 + 255) / 256, 256, 0, stream>>>(Whh, Bh, 128, 384, 128, 1);

  // ---- x -> bf16 ----
  k_f2bf<<<(int)(((size_t)N * 16 + 255) / 256), 256, 0, stream>>>(x, x_bf, (size_t)N * 16);

  // ---- degree -> dinv ----
  k_fill1<<<nb, 256, 0, stream>>>(dinv, N);
  k_scatter_deg<<<(E + 255) / 256, 256, 0, stream>>>(dstI, ew, dinv, E);
  k_rsqrt<<<nb, 256, 0, stream>>>(dinv, N);

  // ---- CSR build ----
  k_zero_i<<<nb, 256, 0, stream>>>(cnt, N);
  k_count<<<(E + 255) / 256, 256, 0, stream>>>(dstI, cnt, E);
  k_scan_block<<<nb, 256, 0, stream>>>(cnt, partial, bsum, N);
  k_scan_sums<<<1, 512, 0, stream>>>(bsum, nb);
  k_scan_add<<<nb, 256, 0, stream>>>(partial, bsum, rowptr, cursor, N);
  k_csr_fill<<<(E + 255) / 256, 256, 0, stream>>>(
      srcI, dstI, ew, dinv, cursor, csr, E);

  int gwave = (N + 127) / 128;  // 4 waves x 32 rows per block

  // xh = relu(x @ linW + linB)  [bf16 out]
  k_mfma_gemm<true, true><<<gwave, 256, 0, stream>>>(x_bf, linWp, linB, xh_bf, N);

  // GRU #1 (h0 -> h)
  k_gru_mfma<<<gwave, 256, 0, stream>>>(xh_bf, h0, h, Bi, Bh, bih, bhh, N);

  int ggat = (N + 3) / 4;     // 1 node per wave, 4 waves/block
  for (int l = 0; l < 3; ++l) {
    k_mfma_gemm<false, false><<<gwave, 256, 0, stream>>>(
        xh_bf, convWp + (size_t)l * 128 * 128, nullptr, xw_bf, N);
    k_gather<<<ggat, 256, 0, stream>>>(
        rowptr, csr, (const unsigned*)xw_bf, dinv, convB + (size_t)l * 128,
        (unsigned*)xh_bf, N);
    k_gru_mfma<<<gwave, 256, 0, stream>>>(xh_bf, h, h, Bi, Bh, bih, bhh, N);
  }

  // out = h @ fcW + fcB (fp32)
  dim3 g40(1, (N + 63) / 64);
  k_gemm128<false, true><<<g40, 256, 0, stream>>>(h, fcW, fcB, (float*)d_out, N, 40);
}

// Round 7
// 999.214 us; speedup vs baseline: 1.1524x; 1.1524x over previous
//
#include <hip/hip_runtime.h>
#include <hip/hip_bf16.h>
#include <math.h>

typedef __attribute__((ext_vector_type(8))) short bf8_t;   // 8 x bf16 (4 VGPRs)
typedef __attribute__((ext_vector_type(4))) float f4_t;    // MFMA accumulator
typedef __attribute__((ext_vector_type(8))) unsigned short us8_t;

__device__ inline unsigned short f2bf(float f) {
  union { float f; unsigned u; } x; x.f = f;
  unsigned r = x.u + 0x7FFF + ((x.u >> 16) & 1);   // RNE
  return (unsigned short)(r >> 16);
}
__device__ inline float bf2f(unsigned short b) {
  union { unsigned u; float f; } x; x.u = ((unsigned)b) << 16;
  return x.f;
}
__device__ inline float bflo(unsigned v) {
  union { unsigned u; float f; } x; x.u = v << 16; return x.f;
}
__device__ inline float bfhi(unsigned v) {
  union { unsigned u; float f; } x; x.u = v & 0xFFFF0000u; return x.f;
}

// async global->LDS copy, 16B per lane; LDS dest = base + lane*16 (HW rule)
__device__ inline void async_copy16(const void* g, void* l) {
  __builtin_amdgcn_global_load_lds(
      (const __attribute__((address_space(1))) unsigned int*)g,
      (__attribute__((address_space(3))) unsigned int*)l, 16, 0, 0);
}

// ---------------------------------------------------------------------------
// small utility kernels
// ---------------------------------------------------------------------------

__global__ void k_fill1(float* __restrict__ p, int n) {
  int i = blockIdx.x * blockDim.x + threadIdx.x;
  if (i < n) p[i] = 1.0f;
}

__global__ void k_zero_i(int* __restrict__ p, int n) {
  int i = blockIdx.x * blockDim.x + threadIdx.x;
  if (i < n) p[i] = 0;
}

__global__ void k_scatter_deg(const int* __restrict__ dst, const float* __restrict__ ew,
                              float* __restrict__ deg, int E) {
  int e = blockIdx.x * blockDim.x + threadIdx.x;
  if (e < E) atomicAdd(&deg[dst[e]], ew[e]);
}

__global__ void k_count(const int* __restrict__ dst, int* __restrict__ cnt, int E) {
  int e = blockIdx.x * blockDim.x + threadIdx.x;
  if (e < E) atomicAdd(&cnt[dst[e]], 1);
}

__global__ void k_rsqrt(float* __restrict__ p, int n) {
  int i = blockIdx.x * blockDim.x + threadIdx.x;
  if (i < n) p[i] = rsqrtf(p[i]);
}

// fp32 -> bf16 bulk convert (n multiple of 8)
__global__ void k_f2bf(const float* __restrict__ in, unsigned short* __restrict__ out,
                       size_t n8) {
  size_t i = (size_t)blockIdx.x * blockDim.x + threadIdx.x;
  if (i >= n8) return;
  const float4* p = (const float4*)(in + i * 8);
  float4 a = p[0], b = p[1];
  us8_t v;
  v[0] = f2bf(a.x); v[1] = f2bf(a.y); v[2] = f2bf(a.z); v[3] = f2bf(a.w);
  v[4] = f2bf(b.x); v[5] = f2bf(b.y); v[6] = f2bf(b.z); v[7] = f2bf(b.w);
  *(us8_t*)(out + i * 8) = v;
}

// pack weight matrix into MFMA B-fragment order (16x16x32 bf16).
// fragment (n0,k0): lane holds B[k0*32+(lane>>4)*8+j][n0*16+(lane&15)], j=0..7
__global__ void k_packB(const float* __restrict__ W, unsigned short* __restrict__ out,
                        int K, int Ncols, int ldw, int trans) {
  int idx = blockIdx.x * 256 + threadIdx.x;
  int total = (Ncols / 16) * (K / 32) * 64;
  if (idx >= total) return;
  int lane = idx & 63;
  int frag = idx >> 6;
  int kt = K / 32;
  int k0 = frag % kt;
  int n0 = frag / kt;
  int n = n0 * 16 + (lane & 15);
  int kbase = k0 * 32 + (lane >> 4) * 8;
  us8_t v;
#pragma unroll
  for (int j = 0; j < 8; ++j) {
    int k = kbase + j;
    float f = trans ? W[(size_t)n * ldw + k] : W[(size_t)k * ldw + n];
    v[j] = f2bf(f);
  }
  *(us8_t*)(out + (size_t)idx * 8) = v;
}

// ---------------------------------------------------------------------------
// hierarchical scan for rowptr (N up to 512*256 = 131072)
// ---------------------------------------------------------------------------

__global__ __launch_bounds__(256) void k_scan_block(
    const int* __restrict__ cnt, int* __restrict__ partial,
    int* __restrict__ bsum, int n) {
  __shared__ int s[256];
  int tid = threadIdx.x;
  int i = blockIdx.x * 256 + tid;
  s[tid] = (i < n) ? cnt[i] : 0;
  __syncthreads();
#pragma unroll
  for (int d = 1; d < 256; d <<= 1) {
    int t = (tid >= d) ? s[tid - d] : 0;
    __syncthreads();
    s[tid] += t;
    __syncthreads();
  }
  if (i < n) partial[i] = s[tid];
  if (tid == 255) bsum[blockIdx.x] = s[255];
}

__global__ __launch_bounds__(512) void k_scan_sums(int* __restrict__ bsum, int nb) {
  __shared__ int s[512];
  int tid = threadIdx.x;
  s[tid] = (tid < nb) ? bsum[tid] : 0;
  __syncthreads();
#pragma unroll
  for (int d = 1; d < 512; d <<= 1) {
    int t = (tid >= d) ? s[tid - d] : 0;
    __syncthreads();
    s[tid] += t;
    __syncthreads();
  }
  if (tid < nb) bsum[tid] = s[tid];
}

__global__ __launch_bounds__(256) void k_scan_add(
    const int* __restrict__ partial, const int* __restrict__ bsum,
    int* __restrict__ rowptr, int* __restrict__ cursor, int n) {
  int i = blockIdx.x * 256 + threadIdx.x;
  if (i == 0) { rowptr[0] = 0; cursor[0] = 0; }
  if (i < n) {
    int v = partial[i] + (blockIdx.x > 0 ? bsum[blockIdx.x - 1] : 0);
    rowptr[i + 1] = v;
    if (i + 1 < n) cursor[i + 1] = v;
  }
}

__global__ __launch_bounds__(256) void k_csr_fill(
    const int* __restrict__ src, const int* __restrict__ dst,
    const float* __restrict__ ew, const float* __restrict__ dinv,
    int* __restrict__ cursor, int2* __restrict__ csr, int E) {
  int e = blockIdx.x * 256 + threadIdx.x;
  if (e >= E) return;
  int s = src[e], d = dst[e];
  float w = dinv[s] * ew[e] * dinv[d];
  int pos = atomicAdd(&cursor[d], 1);
  csr[pos] = make_int2(s, __float_as_int(w));
}

// ---------------------------------------------------------------------------
// MFMA GEMM with LDS-staged B: C[M,128] = A[M,128]@B[128,128] (+bias)(+relu).
// Block = 4 waves x 16 rows. All 32 KB of packed B staged once via
// global_load_lds, then fed from LDS (ds_read_b128).
// ---------------------------------------------------------------------------

template<bool RELU, bool BIAS>
__global__ __launch_bounds__(256) void k_mfma_gemm(
    const unsigned short* __restrict__ A, const unsigned short* __restrict__ Bp,
    const float* __restrict__ bias, unsigned short* __restrict__ C, int M) {
  __shared__ unsigned char smem[32 * 1024];
  int wave = threadIdx.x >> 6, lane = threadIdx.x & 63;
  int row0 = (blockIdx.x * 4 + wave) * 16;
  int m = lane & 15, q = lane >> 4;

  // stage: 32 fragments of 1 KB; wave w stages f = 8w..8w+7
#pragma unroll
  for (int i = 0; i < 8; ++i) {
    int f = wave * 8 + i;
    async_copy16((const unsigned char*)Bp + (size_t)f * 1024 + lane * 16,
                 smem + f * 1024);
  }
  __syncthreads();
  if (row0 >= M) return;

  int arow = row0 + m; if (arow >= M) arow = M - 1;
  bf8_t a[4];
#pragma unroll
  for (int k0 = 0; k0 < 4; ++k0)
    a[k0] = *(const bf8_t*)(A + (size_t)arow * 128 + k0 * 32 + q * 8);

#pragma unroll
  for (int n0 = 0; n0 < 8; ++n0) {
    f4_t acc = {};
#pragma unroll
    for (int k0 = 0; k0 < 4; ++k0) {
      bf8_t b = *(const bf8_t*)(smem + (n0 * 4 + k0) * 1024 + lane * 16);
      acc = __builtin_amdgcn_mfma_f32_16x16x32_bf16(a[k0], b, acc, 0, 0, 0);
    }
    int col = n0 * 16 + m;
    float bs = BIAS ? bias[col] : 0.f;
#pragma unroll
    for (int r = 0; r < 4; ++r) {
      int grow = row0 + q * 4 + r;
      if (grow < M) {
        float v = acc[r] + bs;
        if (RELU) v = fmaxf(v, 0.f);
        C[(size_t)grow * 128 + col] = f2bf(v);
      }
    }
  }
}

// ---------------------------------------------------------------------------
// Fused MFMA GRU with LDS-staged B. Block = 4 waves x 16 rows.
// Loop over 8 gate-groups; per group stage 24 KB (6 fragment-sets x 4 k) of
// Bi/Bh via global_load_lds, sync, MFMA from LDS, sync, then issue next
// group's staging so its latency hides under the gate-math epilogue.
// In-place h safe: wave reads/writes only its own 16 rows.
// ---------------------------------------------------------------------------

__global__ __launch_bounds__(256) void k_gru_mfma(
    const unsigned short* __restrict__ xh,  // [M,128] bf16
    const float* h_in,                      // [M,128] fp32
    float* h_out,                           // [M,128] fp32 (may alias h_in)
    const unsigned short* __restrict__ Bi,  // packed WihT (K=128, Ncols=384)
    const unsigned short* __restrict__ Bh,  // packed WhhT
    const float* __restrict__ bih, const float* __restrict__ bhh, int M) {
  __shared__ unsigned char smem[24 * 1024];
  int wave = threadIdx.x >> 6, lane = threadIdx.x & 63;
  int row0 = (blockIdx.x * 4 + wave) * 16;
  int m = lane & 15, q = lane >> 4;
  int arow = row0 + m; if (arow >= M) arow = M - 1;

  bf8_t ax[4], ah[4];
#pragma unroll
  for (int k0 = 0; k0 < 4; ++k0) {
    ax[k0] = *(const bf8_t*)(xh + (size_t)arow * 128 + k0 * 32 + q * 8);
    const float* hp = h_in + (size_t)arow * 128 + k0 * 32 + q * 8;
    float4 h0 = *(const float4*)hp;
    float4 h1 = *(const float4*)(hp + 4);
    bf8_t t;
    t[0] = (short)f2bf(h0.x); t[1] = (short)f2bf(h0.y);
    t[2] = (short)f2bf(h0.z); t[3] = (short)f2bf(h0.w);
    t[4] = (short)f2bf(h1.x); t[5] = (short)f2bf(h1.y);
    t[6] = (short)f2bf(h1.z); t[7] = (short)f2bf(h1.w);
    ah[k0] = t;
  }

  // stage group g: 6 sets (Bi r/z/n, Bh r/z/n) x 4 k-frags; wave w does k0=w
  auto stage = [&](int g) {
#pragma unroll
    for (int s = 0; s < 6; ++s) {
      int cc = g + 8 * (s >= 3 ? s - 3 : s);
      const unsigned short* src = (s < 3) ? Bi : Bh;
      int f = s * 4 + wave;
      async_copy16((const unsigned char*)src + ((size_t)(cc * 4 + wave)) * 1024 + lane * 16,
                   smem + f * 1024);
    }
  };

  stage(0);
  for (int g = 0; g < 8; ++g) {
    __syncthreads();   // staging of g complete (vmcnt drained by barrier)
    f4_t air = {}, aiz = {}, ain = {}, ahr = {}, ahz = {}, ahn = {};
#pragma unroll
    for (int k0 = 0; k0 < 4; ++k0) {
      bf8_t br = *(const bf8_t*)(smem + (0 * 4 + k0) * 1024 + lane * 16);
      bf8_t bz = *(const bf8_t*)(smem + (1 * 4 + k0) * 1024 + lane * 16);
      bf8_t bn = *(const bf8_t*)(smem + (2 * 4 + k0) * 1024 + lane * 16);
      bf8_t cr = *(const bf8_t*)(smem + (3 * 4 + k0) * 1024 + lane * 16);
      bf8_t cz = *(const bf8_t*)(smem + (4 * 4 + k0) * 1024 + lane * 16);
      bf8_t cn = *(const bf8_t*)(smem + (5 * 4 + k0) * 1024 + lane * 16);
      air = __builtin_amdgcn_mfma_f32_16x16x32_bf16(ax[k0], br, air, 0, 0, 0);
      aiz = __builtin_amdgcn_mfma_f32_16x16x32_bf16(ax[k0], bz, aiz, 0, 0, 0);
      ain = __builtin_amdgcn_mfma_f32_16x16x32_bf16(ax[k0], bn, ain, 0, 0, 0);
      ahr = __builtin_amdgcn_mfma_f32_16x16x32_bf16(ah[k0], cr, ahr, 0, 0, 0);
      ahz = __builtin_amdgcn_mfma_f32_16x16x32_bf16(ah[k0], cz, ahz, 0, 0, 0);
      ahn = __builtin_amdgcn_mfma_f32_16x16x32_bf16(ah[k0], cn, ahn, 0, 0, 0);
    }
    __syncthreads();   // all waves done reading LDS for g
    if (g < 7) stage(g + 1);   // async: latency hides under epilogue below

    int col = g * 16 + m;
    float bir_ = bih[col], biz_ = bih[col + 128], bin_ = bih[col + 256];
    float bhr_ = bhh[col], bhz_ = bhh[col + 128], bhn_ = bhh[col + 256];
#pragma unroll
    for (int r = 0; r < 4; ++r) {
      int grow = row0 + q * 4 + r;
      if (grow < M) {
        float hprev = h_in[(size_t)grow * 128 + col];
        float rr = 1.f / (1.f + expf(-(air[r] + bir_ + ahr[r] + bhr_)));
        float zz = 1.f / (1.f + expf(-(aiz[r] + biz_ + ahz[r] + bhz_)));
        float nn = tanhf(ain[r] + bin_ + rr * (ahn[r] + bhn_));
        h_out[(size_t)grow * 128 + col] = (1.f - zz) * nn + zz * hprev;
      }
    }
  }
}

// ---------------------------------------------------------------------------
// fp32 GEMM (final fc layer)
// ---------------------------------------------------------------------------

template<bool RELU, bool BIAS>
__global__ __launch_bounds__(256) void k_gemm128(
    const float* __restrict__ A, const float* __restrict__ B,
    const float* __restrict__ bias, float* __restrict__ C, int M, int Nc) {
  __shared__ float As[64][36];
  __shared__ float Bs[32][64];
  int tid = threadIdx.x;
  int tx = tid & 15, ty = tid >> 4;
  int row0 = blockIdx.y * 64, col0 = blockIdx.x * 64;
  float acc[4][4] = {};

  for (int k0 = 0; k0 < 128; k0 += 32) {
#pragma unroll
    for (int i = 0; i < 2; ++i) {
      int f = tid + i * 256;
      int r = f >> 3, c4 = f & 7;
      int gr = row0 + r;
      float4 v = make_float4(0.f, 0.f, 0.f, 0.f);
      if (gr < M) v = *(const float4*)(A + (size_t)gr * 128 + k0 + c4 * 4);
      *(float4*)(&As[r][c4 * 4]) = v;
    }
#pragma unroll
    for (int i = 0; i < 2; ++i) {
      int f = tid + i * 256;
      int r = f >> 4, c4 = f & 15;
      int gc = col0 + c4 * 4;
      float4 v = make_float4(0.f, 0.f, 0.f, 0.f);
      if (gc + 3 < Nc) v = *(const float4*)(B + (size_t)(k0 + r) * Nc + gc);
      *(float4*)(&Bs[r][c4 * 4]) = v;
    }
    __syncthreads();
#pragma unroll
    for (int kk = 0; kk < 32; ++kk) {
      float4 b = *(float4*)(&Bs[kk][tx * 4]);
      float a0 = As[ty * 4 + 0][kk];
      float a1 = As[ty * 4 + 1][kk];
      float a2 = As[ty * 4 + 2][kk];
      float a3 = As[ty * 4 + 3][kk];
      acc[0][0] += a0 * b.x; acc[0][1] += a0 * b.y; acc[0][2] += a0 * b.z; acc[0][3] += a0 * b.w;
      acc[1][0] += a1 * b.x; acc[1][1] += a1 * b.y; acc[1][2] += a1 * b.z; acc[1][3] += a1 * b.w;
      acc[2][0] += a2 * b.x; acc[2][1] += a2 * b.y; acc[2][2] += a2 * b.z; acc[2][3] += a2 * b.w;
      acc[3][0] += a3 * b.x; acc[3][1] += a3 * b.y; acc[3][2] += a3 * b.z; acc[3][3] += a3 * b.w;
    }
    __syncthreads();
  }

#pragma unroll
  for (int i = 0; i < 4; ++i) {
    int gr = row0 + ty * 4 + i;
    if (gr >= M) continue;
#pragma unroll
    for (int j = 0; j < 4; ++j) {
      int gc = col0 + tx * 4 + j;
      if (gc >= Nc) continue;
      float v = acc[i][j];
      if (BIAS) v += bias[gc];
      if (RELU) v = fmaxf(v, 0.f);
      C[(size_t)gr * Nc + gc] = v;
    }
  }
}

// ---------------------------------------------------------------------------
// CSR gather aggregation: 1 node per wave, lane owns 2 channels (packed uint).
// ---------------------------------------------------------------------------

__global__ __launch_bounds__(256) void k_gather(
    const int* __restrict__ rowptr, const int2* __restrict__ csr,
    const unsigned* __restrict__ xw,   // [N,64] packed bf16x2
    const float* __restrict__ dinv, const float* __restrict__ bias,
    unsigned* __restrict__ out, int N) {
  int wave = threadIdx.x >> 6;
  int lane = threadIdx.x & 63;
  int node = __builtin_amdgcn_readfirstlane(blockIdx.x * 4 + wave);
  if (node >= N) return;
  int beg = __builtin_amdgcn_readfirstlane(rowptr[node]);
  int end = __builtin_amdgcn_readfirstlane(rowptr[node + 1]);

  float accl = 0.f, acch = 0.f;
  int k = beg;
  for (; k + 4 <= end; k += 4) {
    int2 e0 = csr[k], e1 = csr[k + 1], e2 = csr[k + 2], e3 = csr[k + 3];
    unsigned v0 = xw[((size_t)e0.x << 6) + lane];
    unsigned v1 = xw[((size_t)e1.x << 6) + lane];
    unsigned v2 = xw[((size_t)e2.x << 6) + lane];
    unsigned v3 = xw[((size_t)e3.x << 6) + lane];
    float w0 = __int_as_float(e0.y), w1 = __int_as_float(e1.y);
    float w2 = __int_as_float(e2.y), w3 = __int_as_float(e3.y);
    accl += bflo(v0) * w0; acch += bfhi(v0) * w0;
    accl += bflo(v1) * w1; acch += bfhi(v1) * w1;
    accl += bflo(v2) * w2; acch += bfhi(v2) * w2;
    accl += bflo(v3) * w3; acch += bfhi(v3) * w3;
  }
  for (; k < end; ++k) {
    int2 e = csr[k];
    unsigned v = xw[((size_t)e.x << 6) + lane];
    float w = __int_as_float(e.y);
    accl += bflo(v) * w; acch += bfhi(v) * w;
  }

  float di = dinv[node];
  float sn = di * di;
  unsigned vs = xw[((size_t)node << 6) + lane];
  float2 b = *(const float2*)(bias + lane * 2);
  float rl = fmaxf(accl + bflo(vs) * sn + b.x, 0.f);
  float rh = fmaxf(acch + bfhi(vs) * sn + b.y, 0.f);
  unsigned o = (unsigned)f2bf(rl) | ((unsigned)f2bf(rh) << 16);
  out[((size_t)node << 6) + lane] = o;
}

// ---------------------------------------------------------------------------

extern "C" void kernel_launch(void* const* d_in, const int* in_sizes, int n_in,
                              void* d_out, int out_size, void* d_ws, size_t ws_size,
                              hipStream_t stream) {
  const float* x    = (const float*)d_in[0];
  const int*   ei   = (const int*)d_in[1];
  const float* ew   = (const float*)d_in[2];
  const float* h0   = (const float*)d_in[3];
  const float* linW = (const float*)d_in[4];
  const float* linB = (const float*)d_in[5];
  const float* convW= (const float*)d_in[6];
  const float* convB= (const float*)d_in[7];
  const float* Wih  = (const float*)d_in[8];
  const float* Whh  = (const float*)d_in[9];
  const float* bih  = (const float*)d_in[10];
  const float* bhh  = (const float*)d_in[11];
  const float* fcW  = (const float*)d_in[12];
  const float* fcB  = (const float*)d_in[13];

  int N = in_sizes[0] / 128;
  int E = in_sizes[1] / 2;
  const int* srcI = ei;
  const int* dstI = ei + E;
  int nb = (N + 255) / 256;

  // ---- workspace layout ----
  float* ws = (float*)d_ws;
  size_t off = 0;
  float* dinv = ws + off; off += (size_t)N;
  if (off & 1) off++;                       // 8B-align what follows
  float* h    = ws + off; off += (size_t)N * 128;
  int* iws = (int*)(ws + off);              // 8B-aligned
  size_t ioff = 0;
  int2* csr    = (int2*)iws; ioff += (size_t)2 * E;
  int* cnt     = iws + ioff; ioff += (size_t)N;
  int* partial = iws + ioff; ioff += (size_t)N;
  int* bsum    = iws + ioff; ioff += 512;
  int* rowptr  = iws + ioff; ioff += (size_t)N + 1;
  int* cursor  = iws + ioff; ioff += (size_t)N;
  ioff = (ioff + 3) & ~(size_t)3;           // 16B-align ushort area
  unsigned short* usws = (unsigned short*)(iws + ioff);
  size_t uoff = 0;
  unsigned short* x_bf   = usws + uoff; uoff += (size_t)N * 128;
  unsigned short* xh_bf  = usws + uoff; uoff += (size_t)N * 128;
  unsigned short* xw_bf  = usws + uoff; uoff += (size_t)N * 128;
  unsigned short* linWp  = usws + uoff; uoff += 128 * 128;
  unsigned short* convWp = usws + uoff; uoff += 3 * 128 * 128;
  unsigned short* Bi     = usws + uoff; uoff += 384 * 128;
  unsigned short* Bh     = usws + uoff; uoff += 384 * 128;

  // ---- weight packing ----
  k_packB<<<(8 * 4 * 64 + 255) / 256, 256, 0, stream>>>(linW, linWp, 128, 128, 128, 0);
  for (int l = 0; l < 3; ++l)
    k_packB<<<(8 * 4 * 64 + 255) / 256, 256, 0, stream>>>(
        convW + (size_t)l * 128 * 128, convWp + (size_t)l * 128 * 128, 128, 128, 128, 0);
  k_packB<<<(24 * 4 * 64 + 255) / 256, 256, 0, stream>>>(Wih, Bi, 128, 384, 128, 1);
  k_packB<<<(24 * 4 * 64 + 255) / 256, 256, 0, stream>>>(Whh, Bh, 128, 384, 128, 1);

  // ---- x -> bf16 ----
  k_f2bf<<<(int)(((size_t)N * 16 + 255) / 256), 256, 0, stream>>>(x, x_bf, (size_t)N * 16);

  // ---- degree -> dinv ----
  k_fill1<<<nb, 256, 0, stream>>>(dinv, N);
  k_scatter_deg<<<(E + 255) / 256, 256, 0, stream>>>(dstI, ew, dinv, E);
  k_rsqrt<<<nb, 256, 0, stream>>>(dinv, N);

  // ---- CSR build ----
  k_zero_i<<<nb, 256, 0, stream>>>(cnt, N);
  k_count<<<(E + 255) / 256, 256, 0, stream>>>(dstI, cnt, E);
  k_scan_block<<<nb, 256, 0, stream>>>(cnt, partial, bsum, N);
  k_scan_sums<<<1, 512, 0, stream>>>(bsum, nb);
  k_scan_add<<<nb, 256, 0, stream>>>(partial, bsum, rowptr, cursor, N);
  k_csr_fill<<<(E + 255) / 256, 256, 0, stream>>>(
      srcI, dstI, ew, dinv, cursor, csr, E);

  int gwave = (N + 63) / 64;  // 4 waves x 16 rows per block

  // xh = relu(x @ linW + linB)  [bf16 out]
  k_mfma_gemm<true, true><<<gwave, 256, 0, stream>>>(x_bf, linWp, linB, xh_bf, N);

  // GRU #1 (h0 -> h)
  k_gru_mfma<<<gwave, 256, 0, stream>>>(xh_bf, h0, h, Bi, Bh, bih, bhh, N);

  int ggat = (N + 3) / 4;     // 1 node per wave, 4 waves/block
  for (int l = 0; l < 3; ++l) {
    k_mfma_gemm<false, false><<<gwave, 256, 0, stream>>>(
        xh_bf, convWp + (size_t)l * 128 * 128, nullptr, xw_bf, N);
    k_gather<<<ggat, 256, 0, stream>>>(
        rowptr, csr, (const unsigned*)xw_bf, dinv, convB + (size_t)l * 128,
        (unsigned*)xh_bf, N);
    k_gru_mfma<<<gwave, 256, 0, stream>>>(xh_bf, h, h, Bi, Bh, bih, bhh, N);
  }

  // out = h @ fcW + fcB (fp32)
  dim3 g40(1, (N + 63) / 64);
  k_gemm128<false, true><<<g40, 256, 0, stream>>>(h, fcW, fcB, (float*)d_out, N, 40);
}